// Round 3
// baseline (23230.083 us; speedup 1.0000x reference)
//
#include <hip/hip_runtime.h>
#include <hip/hip_bf16.h>

typedef __attribute__((ext_vector_type(8))) short bf16x8;
typedef __attribute__((ext_vector_type(4))) float f32x4;

#define HD   768
#define NB   64
#define NT   256
#define NGATE 3072   // 4*HD

__device__ __forceinline__ float fast_sig(float x) { return 1.f / (1.f + __expf(-x)); }
__device__ __forceinline__ float fast_tanh(float x) {
  float t = __expf(-2.f * fabsf(x));
  float r = (1.f - t) / (1.f + t);
  return x < 0.f ? -r : r;
}

// ---------------------------------------------------------------------------
// Core per-step GEMM: gates[b][n'] = sum_k A[b][k] * W[n'][k]
//   A is split: k < K0 -> A0 (row stride strideA0), k >= K0 -> A1 (stride 768)
//   W is bf16 row-major [3072][K], rows pre-permuted n' = j*4 + gate
//   Block tile: 64 (all b) x 32 n'.  4 waves, wave w does rows 16w..16w+15.
//   Result left in LDS gl[64][33].
// MFMA 16x16x32 bf16 layouts (gfx950):
//   A: lane l -> row l%16, k = 8*(l/16)+e ;  B: lane l -> col l%16, same k
//   D: lane l, reg r -> row 4*(l/16)+r, col l%16
// ---------------------------------------------------------------------------
__device__ __forceinline__ void mfma_gates(
    const __hip_bfloat16* __restrict__ W, int K,
    const __hip_bfloat16* __restrict__ A0, long strideA0, int K0,
    const __hip_bfloat16* __restrict__ A1,
    int n_base, float (*gl)[33])
{
  int tid = threadIdx.x;
  int w  = tid >> 6;
  int l  = tid & 63;
  int lr = l & 15, lh = l >> 4;
  f32x4 acc0 = {0.f, 0.f, 0.f, 0.f};
  f32x4 acc1 = {0.f, 0.f, 0.f, 0.f};
  int bA = 16 * w + lr;
  const __hip_bfloat16* a0p = A0 + (long)bA * strideA0;
  const __hip_bfloat16* a1p = A1 + bA * HD;
  const __hip_bfloat16* b0p = W + (long)(n_base + lr) * K;
  const __hip_bfloat16* b1p = W + (long)(n_base + 16 + lr) * K;
  int kk = 8 * lh;
  #pragma unroll 4
  for (int k0 = 0; k0 < K; k0 += 32) {
    int ka = k0 + kk;
    bf16x8 av  = (ka < K0) ? *(const bf16x8*)(a0p + ka)
                           : *(const bf16x8*)(a1p + (ka - K0));
    bf16x8 bv0 = *(const bf16x8*)(b0p + ka);
    bf16x8 bv1 = *(const bf16x8*)(b1p + ka);
    acc0 = __builtin_amdgcn_mfma_f32_16x16x32_bf16(av, bv0, acc0, 0, 0, 0);
    acc1 = __builtin_amdgcn_mfma_f32_16x16x32_bf16(av, bv1, acc1, 0, 0, 0);
  }
  #pragma unroll
  for (int r = 0; r < 4; ++r) {
    gl[16 * w + 4 * lh + r][lr]      = acc0[r];
    gl[16 * w + 4 * lh + r][16 + lr] = acc1[r];
  }
}

// ---------------------------------------------------------------------------
// Setup kernels
// ---------------------------------------------------------------------------
__global__ void cvt_bf16_kernel(const float* __restrict__ src,
                                __hip_bfloat16* __restrict__ dst, long n)
{
  long i = (long)blockIdx.x * blockDim.x + threadIdx.x;
  long stride = (long)gridDim.x * blockDim.x;
  for (; i < n; i += stride) dst[i] = __float2bfloat16(src[i]);
}

// dst[n'][k] with n' = j*4 + g (gate-interleaved), K = Kih + 768
// k < Kih -> Wih[g*768+j][k]; else Whh[g*768+j][k-Kih]
__global__ void pack_w_kernel(const float* __restrict__ Wih,
                              const float* __restrict__ Whh,
                              __hip_bfloat16* __restrict__ dst, int Kih)
{
  int K = Kih + HD;
  long total = (long)NGATE * K;
  long stride = (long)gridDim.x * blockDim.x;
  for (long idx = (long)blockIdx.x * blockDim.x + threadIdx.x; idx < total; idx += stride) {
    int np = (int)(idx / K), k = (int)(idx % K);
    int j = np >> 2, g = np & 3;
    int n = g * HD + j;
    float v = (k < Kih) ? Wih[(long)n * Kih + k] : Whh[(long)n * HD + (k - Kih)];
    dst[idx] = __float2bfloat16(v);
  }
}

__global__ void fill_sentinel(float* out, int n, float v)
{
  int i = blockIdx.x * blockDim.x + threadIdx.x;
  if (i < n) out[i] = v;
}

// ---------------------------------------------------------------------------
// Phase 1: BiLSTM step. Grid = 192 blocks: blk<96 fwd, else bwd. nt = blk%96.
// ---------------------------------------------------------------------------
__global__ __launch_bounds__(256) void bilstm_step(
    int step,
    int par,
    const __hip_bfloat16* __restrict__ X16,   // [64][256][768] bf16
    const __hip_bfloat16* __restrict__ WF,    // [3072][1536]
    const __hip_bfloat16* __restrict__ WB,
    const float* __restrict__ bF, const float* __restrict__ bB,
    __hip_bfloat16* __restrict__ H16,         // [2 par][2 dir][64][768]
    float* __restrict__ C32,                  // [2 dir][64][768]
    __hip_bfloat16* __restrict__ L16)         // [64][256][1536]
{
  __shared__ float gl[64][33];
  int blk = blockIdx.x;
  int dir = blk / 96, nt = blk % 96;
  int t = dir ? (255 - step) : step;
  const __hip_bfloat16* W    = dir ? WB : WF;
  const float*          bias = dir ? bB : bF;
  const __hip_bfloat16* A0 = X16 + (long)t * HD;              // + b*(256*768)
  const __hip_bfloat16* H  = H16 + (long)(par * 2 + dir) * (NB * HD);
  __hip_bfloat16* Hn       = H16 + (long)((par ^ 1) * 2 + dir) * (NB * HD);
  float* C = C32 + (long)dir * (NB * HD);

  mfma_gates(W, 1536, A0, (long)NT * HD, 768, H, nt * 32, gl);
  __syncthreads();

  int tid = threadIdx.x;
  #pragma unroll
  for (int u = 0; u < 2; ++u) {
    int e = tid * 2 + u;
    int b = e >> 3, jj = e & 7;
    int j = nt * 8 + jj;
    float vi = gl[b][4 * jj + 0] + bias[j];
    float vf = gl[b][4 * jj + 1] + bias[HD + j];
    float vg = gl[b][4 * jj + 2] + bias[2 * HD + j];
    float vo = gl[b][4 * jj + 3] + bias[3 * HD + j];
    float si = fast_sig(vi), sf = fast_sig(vf), so = fast_sig(vo);
    float tg = fast_tanh(vg);
    int idx = b * HD + j;
    float c = sf * C[idx] + si * tg;
    float h = so * fast_tanh(c);
    C[idx] = c;
    __hip_bfloat16 hb = __float2bfloat16(h);
    Hn[idx] = hb;
    L16[((long)b * NT + t) * 1536 + dir * HD + j] = hb;
  }
}

// ---------------------------------------------------------------------------
// cls x-part: out[b][t][o] = cls_b[o] + sum_k L16[b][t][k]*clsW[o][768+k], t>=1
// block t==0 writes pred0 = (-1, 1).
// ---------------------------------------------------------------------------
__global__ __launch_bounds__(256) void clsx_kernel(
    const __hip_bfloat16* __restrict__ L16,
    const float* __restrict__ clsW, const float* __restrict__ clsb,
    float* __restrict__ out)
{
  int t = blockIdx.x;
  int tid = threadIdx.x;
  if (t == 0) {
    if (tid < 128) {
      int b = tid >> 1, o = tid & 1;
      out[((long)b * NT) * 2 + o] = o ? 1.f : -1.f;
    }
    return;
  }
  if (tid >= 128) return;
  int b = tid >> 1, o = tid & 1;
  const __hip_bfloat16* xp = L16 + ((long)b * NT + t) * 1536;
  const float* w = clsW + o * 2304 + HD;
  float s = clsb[o];
  for (int k = 0; k < 1536; ++k) s += __bfloat162float(xp[k]) * w[k];
  out[((long)b * NT + t) * 2 + o] = s;
}

// ---------------------------------------------------------------------------
// Phase 2a: subword cell. grid 96 blocks.
// A = [ lstm_out[:,s] (1536) | h1s (768) ], W = Wsub' [3072][2304]
// ---------------------------------------------------------------------------
__global__ __launch_bounds__(256) void subw_step(
    int s, int par,
    const __hip_bfloat16* __restrict__ L16,
    const __hip_bfloat16* __restrict__ WS,
    const float* __restrict__ bS,
    __hip_bfloat16* __restrict__ H1S,   // [2][64][768]
    float* __restrict__ C1S,            // [64][768]
    __hip_bfloat16* __restrict__ SUBW,  // [64][1536] = [h1 | c1]
    const int* __restrict__ golds)
{
  __shared__ float gl[64][33];
  int nt = blockIdx.x;
  const __hip_bfloat16* A0 = L16 + (long)s * 1536;
  const __hip_bfloat16* H  = H1S + (long)par * (NB * HD);
  __hip_bfloat16* Hn       = H1S + (long)(par ^ 1) * (NB * HD);

  mfma_gates(WS, 2304, A0, (long)NT * 1536, 1536, H, nt * 32, gl);
  __syncthreads();

  int tid = threadIdx.x;
  __hip_bfloat16 zb = __float2bfloat16(0.f);
  #pragma unroll
  for (int u = 0; u < 2; ++u) {
    int e = tid * 2 + u;
    int b = e >> 3, jj = e & 7;
    int j = nt * 8 + jj;
    float vi = gl[b][4 * jj + 0] + bS[j];
    float vf = gl[b][4 * jj + 1] + bS[HD + j];
    float vg = gl[b][4 * jj + 2] + bS[2 * HD + j];
    float vo = gl[b][4 * jj + 3] + bS[3 * HD + j];
    float si = fast_sig(vi), sf = fast_sig(vf), so = fast_sig(vo);
    float tg = fast_tanh(vg);
    int idx = b * HD + j;
    float c1 = sf * C1S[idx] + si * tg;
    float h1 = so * fast_tanh(c1);
    SUBW[b * 1536 + j]      = __float2bfloat16(h1);
    SUBW[b * 1536 + HD + j] = __float2bfloat16(c1);
    int gg = golds[b * NT + s + 1];
    bool push = (gg == 0);
    Hn[idx]  = push ? __float2bfloat16(h1) : zb;
    C1S[idx] = push ? c1 : 0.f;
  }
}

// ---------------------------------------------------------------------------
// Phase 2b: word cell + cls h2-part (atomics). grid 96 blocks.
// A = [ subword h1,c1 (1536) | h2s (768) ], W = Wword' [3072][2304]
// ---------------------------------------------------------------------------
__global__ __launch_bounds__(256) void word_step(
    int s, int par,
    const __hip_bfloat16* __restrict__ SUBW,
    const __hip_bfloat16* __restrict__ WW,
    const float* __restrict__ bW,
    __hip_bfloat16* __restrict__ H2S,   // [2][64][768]
    float* __restrict__ C2S,            // [64][768]
    const int* __restrict__ golds,
    const float* __restrict__ clsW,
    float* __restrict__ out)
{
  __shared__ float gl[64][33];
  int nt = blockIdx.x;
  const __hip_bfloat16* H = H2S + (long)par * (NB * HD);
  __hip_bfloat16* Hn      = H2S + (long)(par ^ 1) * (NB * HD);

  mfma_gates(WW, 2304, SUBW, 1536, 1536, H, nt * 32, gl);
  __syncthreads();

  int tid = threadIdx.x;
  float p0 = 0.f, p1 = 0.f;
  #pragma unroll
  for (int u = 0; u < 2; ++u) {
    int e = tid * 2 + u;
    int b = e >> 3, jj = e & 7;
    int j = nt * 8 + jj;
    float vi = gl[b][4 * jj + 0] + bW[j];
    float vf = gl[b][4 * jj + 1] + bW[HD + j];
    float vg = gl[b][4 * jj + 2] + bW[2 * HD + j];
    float vo = gl[b][4 * jj + 3] + bW[3 * HD + j];
    float si = fast_sig(vi), sf = fast_sig(vf), so = fast_sig(vo);
    float tg = fast_tanh(vg);
    int idx = b * HD + j;
    float c2 = sf * C2S[idx] + si * tg;
    float h2 = so * fast_tanh(c2);
    int gg = golds[b * NT + s + 1];
    bool push = (gg >= 1);
    Hn[idx] = push ? __float2bfloat16(h2) : H[idx];
    if (push) C2S[idx] = c2;
    p0 += h2 * clsW[j];
    p1 += h2 * clsW[2304 + j];
  }
  // reduce 4 lanes (same b = tid>>2) -> 1 atomic pair
  p0 += __shfl_down(p0, 1); p1 += __shfl_down(p1, 1);
  p0 += __shfl_down(p0, 2); p1 += __shfl_down(p1, 2);
  if ((tid & 3) == 0) {
    int b = tid >> 2;
    atomicAdd(&out[((long)b * NT + s + 1) * 2 + 0], p0);
    atomicAdd(&out[((long)b * NT + s + 1) * 2 + 1], p1);
  }
}

// ---------------------------------------------------------------------------
// Host launcher
// ---------------------------------------------------------------------------
extern "C" void kernel_launch(void* const* d_in, const int* in_sizes, int n_in,
                              void* d_out, int out_size, void* d_ws, size_t ws_size,
                              hipStream_t stream)
{
  const float* x     = (const float*)d_in[0];
  const int*   golds = (const int*)d_in[1];
  const float* WihF  = (const float*)d_in[2];
  const float* WhhF  = (const float*)d_in[3];
  const float* bF    = (const float*)d_in[4];
  const float* WihB  = (const float*)d_in[5];
  const float* WhhB  = (const float*)d_in[6];
  const float* bB    = (const float*)d_in[7];
  const float* WihS  = (const float*)d_in[8];
  const float* WhhS  = (const float*)d_in[9];
  const float* bS    = (const float*)d_in[10];
  const float* WihW  = (const float*)d_in[11];
  const float* WhhW  = (const float*)d_in[12];
  const float* bW    = (const float*)d_in[13];
  const float* clsW  = (const float*)d_in[14];
  const float* clsb  = (const float*)d_in[15];
  float* out = (float*)d_out;

  // workspace layout (bytes)
  const size_t OFF_X16  = 0;                     // 64*256*768 bf16   = 25165824
  const size_t OFF_WF   = 25165824;              // 3072*1536 bf16    =  9437184
  const size_t OFF_WB   = 34603008;
  const size_t OFF_WS   = 44040192;              // 3072*2304 bf16    = 14155776
  const size_t OFF_WW   = 58195968;
  const size_t OFF_L16  = 72351744;              // 64*256*1536 bf16  = 50331648
  const size_t OFF_H16  = 122683392;             // 2*2*64*768 bf16   =   393216
  const size_t OFF_H1S  = 123076608;             // 2*64*768 bf16     =   196608
  const size_t OFF_H2S  = 123273216;
  const size_t OFF_C32  = 123469824;             // 2*64*768 f32      =   393216
  const size_t OFF_C1S  = 123863040;             // 64*768 f32        =   196608
  const size_t OFF_C2S  = 124059648;
  const size_t OFF_SUBW = 124256256;             // 64*1536 bf16      =   196608
  const size_t WS_NEEDED = 124452864;

  if (ws_size < WS_NEEDED) {
    // diagnosable failure: sentinel so absmax ~12345 signals "workspace too small"
    fill_sentinel<<<(out_size + 255) / 256, 256, 0, stream>>>(out, out_size, 12345.f);
    return;
  }

  char* ws = (char*)d_ws;
  __hip_bfloat16* X16  = (__hip_bfloat16*)(ws + OFF_X16);
  __hip_bfloat16* WF   = (__hip_bfloat16*)(ws + OFF_WF);
  __hip_bfloat16* WB   = (__hip_bfloat16*)(ws + OFF_WB);
  __hip_bfloat16* WS   = (__hip_bfloat16*)(ws + OFF_WS);
  __hip_bfloat16* WW   = (__hip_bfloat16*)(ws + OFF_WW);
  __hip_bfloat16* L16  = (__hip_bfloat16*)(ws + OFF_L16);
  __hip_bfloat16* H16  = (__hip_bfloat16*)(ws + OFF_H16);
  __hip_bfloat16* H1S  = (__hip_bfloat16*)(ws + OFF_H1S);
  __hip_bfloat16* H2S  = (__hip_bfloat16*)(ws + OFF_H2S);
  float*          C32  = (float*)(ws + OFF_C32);
  float*          C1S  = (float*)(ws + OFF_C1S);
  float*          C2S  = (float*)(ws + OFF_C2S);
  __hip_bfloat16* SUBW = (__hip_bfloat16*)(ws + OFF_SUBW);

  // setup: pack weights (gate-interleaved bf16), convert x, zero states
  pack_w_kernel<<<2048, 256, 0, stream>>>(WihF, WhhF, WF, 768);
  pack_w_kernel<<<2048, 256, 0, stream>>>(WihB, WhhB, WB, 768);
  pack_w_kernel<<<2048, 256, 0, stream>>>(WihS, WhhS, WS, 1536);
  pack_w_kernel<<<2048, 256, 0, stream>>>(WihW, WhhW, WW, 1536);
  cvt_bf16_kernel<<<2048, 256, 0, stream>>>(x, X16, (long)NB * NT * HD);
  hipMemsetAsync(ws + OFF_H16, 0, OFF_SUBW - OFF_H16, stream);

  // phase 1: BiLSTM (fwd + bwd in lockstep)
  for (int s = 0; s < NT; ++s)
    bilstm_step<<<192, 256, 0, stream>>>(s, s & 1, X16, WF, WB, bF, bB, H16, C32, L16);

  // cls x-part + pred0
  clsx_kernel<<<NT, 256, 0, stream>>>(L16, clsW, clsb, out);

  // phase 2: stack-LSTM scan (stacks reduced to gated state carry)
  for (int s = 0; s < NT - 1; ++s) {
    subw_step<<<96, 256, 0, stream>>>(s, s & 1, L16, WS, bS, H1S, C1S, SUBW, golds);
    word_step<<<96, 256, 0, stream>>>(s, s & 1, SUBW, WW, bW, H2S, C2S, golds, clsW, out);
  }
}

// Round 4
// 13482.811 us; speedup vs baseline: 1.7229x; 1.7229x over previous
//
#include <hip/hip_runtime.h>
#include <hip/hip_bf16.h>

typedef __attribute__((ext_vector_type(8))) short bf16x8;
typedef __attribute__((ext_vector_type(4))) float f32x4;

#define HD   768
#define NB   64
#define NT   256
#define NGATE 3072   // 4*HD

__device__ __forceinline__ float fast_sig(float x) { return 1.f / (1.f + __expf(-x)); }
__device__ __forceinline__ float fast_tanh(float x) {
  float t = __expf(-2.f * fabsf(x));
  float r = (1.f - t) / (1.f + t);
  return x < 0.f ? -r : r;
}
__device__ __forceinline__ float bf2f(unsigned short u) {
  union { unsigned i; float f; } v; v.i = ((unsigned)u) << 16; return v.f;
}

// ---------------------------------------------------------------------------
// Device-scope sync primitives (cross-XCD: full agent fences both sides)
// ---------------------------------------------------------------------------
__device__ __forceinline__ int aload(int* p) {
  return __hip_atomic_load(p, __ATOMIC_RELAXED, __HIP_MEMORY_SCOPE_AGENT);
}
__device__ __forceinline__ void aadd(int* p) {
  __hip_atomic_fetch_add(p, 1, __ATOMIC_RELAXED, __HIP_MEMORY_SCOPE_AGENT);
}
__device__ __forceinline__ void spin_until(int* p, int tgt) {
  while (aload(p) < tgt) __builtin_amdgcn_s_sleep(1);
}
// release + arrive + (wait + acquire)
__device__ __forceinline__ void group_barrier(int* ctr, int tgt, bool wait) {
  __syncthreads();
  if (threadIdx.x == 0) {
    __threadfence();                 // release: wbL2 -> coherent point
    aadd(ctr);
    if (wait) { spin_until(ctr, tgt); __threadfence(); }  // acquire: inv
  }
  __syncthreads();
}
// wait-only (optionally acquire)
__device__ __forceinline__ void group_wait(int* ctr, int tgt, bool acq) {
  if (threadIdx.x == 0) {
    spin_until(ctr, tgt);
    if (acq) __threadfence();
  }
  __syncthreads();
}

// ---------------------------------------------------------------------------
// Load a 32-row weight slice into LDS, XOR-swizzled:
//   lds_byte(r, cb) = r*K*2 + (cb ^ ((r&7)<<4))
// Kills the 16-way bank conflict of stride-K ds_read_b128 column reads.
// ---------------------------------------------------------------------------
__device__ __forceinline__ void load_W_lds(unsigned short* Wl,
                                           const __hip_bfloat16* Wg,
                                           int n_base, int K)
{
  int chunksPerRow = (K * 2) / 16;
  int total = 32 * chunksPerRow;
  for (int idx = threadIdx.x; idx < total; idx += 256) {
    int r  = idx / chunksPerRow;
    int cb = (idx % chunksPerRow) * 16;
    bf16x8 v = *(const bf16x8*)((const char*)(Wg + (long)(n_base + r) * K) + cb);
    *(bf16x8*)((char*)Wl + (long)r * (K * 2) + (cb ^ ((r & 7) << 4))) = v;
  }
}

// ---------------------------------------------------------------------------
// Per-step GEMM, B from swizzled LDS: gates[b][n'] = sum_k A[b][k]*W[n'][k]
// A split: k<K0 -> A0 (strideA0), k>=K0 -> A1 (stride 768). Result in gl.
// ---------------------------------------------------------------------------
__device__ __forceinline__ void mfma_gates_lds(
    const unsigned short* Wl, int Kbytes, int nIter, int K0,
    const __hip_bfloat16* __restrict__ A0, long strideA0,
    const __hip_bfloat16* __restrict__ A1,
    float (*gl)[33])
{
  int tid = threadIdx.x;
  int w = tid >> 6, l = tid & 63, lr = l & 15, lh = l >> 4;
  f32x4 acc0 = {0.f, 0.f, 0.f, 0.f};
  f32x4 acc1 = {0.f, 0.f, 0.f, 0.f};
  int bA = 16 * w + lr;
  const __hip_bfloat16* a0p = A0 + (long)bA * strideA0;
  const __hip_bfloat16* a1p = A1 + bA * HD - K0;
  const char* w0 = (const char*)Wl + lr * Kbytes;
  const char* w1 = (const char*)Wl + (16 + lr) * Kbytes;
  int xr = (lr & 7) << 4;
  int kk = 8 * lh;
  #pragma unroll 4
  for (int it = 0; it < nIter; ++it) {
    int ka = it * 32 + kk;
    const __hip_bfloat16* ap = (ka < K0) ? (a0p + ka) : (a1p + ka);
    bf16x8 av = *(const bf16x8*)ap;
    int o = (ka * 2) ^ xr;
    bf16x8 bv0 = *(const bf16x8*)(w0 + o);
    bf16x8 bv1 = *(const bf16x8*)(w1 + o);
    acc0 = __builtin_amdgcn_mfma_f32_16x16x32_bf16(av, bv0, acc0, 0, 0, 0);
    acc1 = __builtin_amdgcn_mfma_f32_16x16x32_bf16(av, bv1, acc1, 0, 0, 0);
  }
  #pragma unroll
  for (int r = 0; r < 4; ++r) {
    gl[16 * w + 4 * lh + r][lr]      = acc0[r];
    gl[16 * w + 4 * lh + r][16 + lr] = acc1[r];
  }
}

// ---------------------------------------------------------------------------
// Setup kernels
// ---------------------------------------------------------------------------
__global__ void cvt_bf16_kernel(const float* __restrict__ src,
                                __hip_bfloat16* __restrict__ dst, long n)
{
  long i = (long)blockIdx.x * blockDim.x + threadIdx.x;
  long stride = (long)gridDim.x * blockDim.x;
  for (; i < n; i += stride) dst[i] = __float2bfloat16(src[i]);
}

// dst[n'][k], n' = j*4 + g; k < Kih -> Wih, else Whh
__global__ void pack_w_kernel(const float* __restrict__ Wih,
                              const float* __restrict__ Whh,
                              __hip_bfloat16* __restrict__ dst, int Kih)
{
  int K = Kih + HD;
  long total = (long)NGATE * K;
  long stride = (long)gridDim.x * blockDim.x;
  for (long idx = (long)blockIdx.x * blockDim.x + threadIdx.x; idx < total; idx += stride) {
    int np = (int)(idx / K), k = (int)(idx % K);
    int j = np >> 2, g = np & 3;
    int n = g * HD + j;
    float v = (k < Kih) ? Wih[(long)n * Kih + k] : Whh[(long)n * HD + (k - Kih)];
    dst[idx] = __float2bfloat16(v);
  }
}

__global__ void fill_sentinel(float* out, int n, float v)
{
  int i = blockIdx.x * blockDim.x + threadIdx.x;
  if (i < n) out[i] = v;
}

// ---------------------------------------------------------------------------
// Phase 1 persistent: BiLSTM, 192 blocks (0-95 fwd, 96-191 bwd), 256 steps.
// W-slice in LDS; c-state in registers; h double-buffered in global;
// per-direction 96-block grid barrier per step.
// ---------------------------------------------------------------------------
__global__ __launch_bounds__(256, 1) void bilstm_persist(
    const __hip_bfloat16* __restrict__ X16,   // [64][256][768]
    const __hip_bfloat16* __restrict__ WF,
    const __hip_bfloat16* __restrict__ WB,
    const float* __restrict__ bF, const float* __restrict__ bB,
    __hip_bfloat16* __restrict__ H16,         // [2 par][2 dir][64][768]
    __hip_bfloat16* __restrict__ L16,         // [64][256][1536]
    int* __restrict__ bars)
{
  __shared__ unsigned short Wl[32 * 1536];    // 96 KiB
  __shared__ float gl[64][33];
  int blk = blockIdx.x, dir = blk / 96, nt = blk % 96;
  load_W_lds(Wl, dir ? WB : WF, nt * 32, 1536);
  const float* bias = dir ? bB : bF;
  int* ctr = bars + dir * 16;
  int tid = threadIdx.x;

  int b_[2], jj_[2], j_[2]; float bv[2][4];
  #pragma unroll
  for (int u = 0; u < 2; ++u) {
    int e = tid * 2 + u;
    b_[u] = e >> 3; jj_[u] = e & 7; j_[u] = nt * 8 + jj_[u];
    bv[u][0] = bias[j_[u]];          bv[u][1] = bias[HD + j_[u]];
    bv[u][2] = bias[2 * HD + j_[u]]; bv[u][3] = bias[3 * HD + j_[u]];
  }
  float cst[2] = {0.f, 0.f};
  __syncthreads();

  for (int s = 0; s < NT; ++s) {
    int par = s & 1;
    int t = dir ? (NT - 1 - s) : s;
    mfma_gates_lds(Wl, 3072, 48, 768,
                   X16 + (long)t * HD, (long)NT * HD,
                   H16 + (long)(par * 2 + dir) * (NB * HD), gl);
    __syncthreads();
    #pragma unroll
    for (int u = 0; u < 2; ++u) {
      float vi = gl[b_[u]][4 * jj_[u] + 0] + bv[u][0];
      float vf = gl[b_[u]][4 * jj_[u] + 1] + bv[u][1];
      float vg = gl[b_[u]][4 * jj_[u] + 2] + bv[u][2];
      float vo = gl[b_[u]][4 * jj_[u] + 3] + bv[u][3];
      float si = fast_sig(vi), sf = fast_sig(vf), so = fast_sig(vo);
      float tg = fast_tanh(vg);
      float c = sf * cst[u] + si * tg;
      cst[u] = c;
      float h = so * fast_tanh(c);
      __hip_bfloat16 hb = __float2bfloat16(h);
      H16[(long)((par ^ 1) * 2 + dir) * (NB * HD) + b_[u] * HD + j_[u]] = hb;
      L16[((long)b_[u] * NT + t) * 1536 + dir * HD + j_[u]] = hb;
    }
    if (s < NT - 1) group_barrier(ctr, 96 * (s + 1), true);
  }
}

// ---------------------------------------------------------------------------
// cls x-part (vectorized) + pred0
// ---------------------------------------------------------------------------
__global__ __launch_bounds__(256) void clsx_kernel(
    const __hip_bfloat16* __restrict__ L16,
    const float* __restrict__ clsW, const float* __restrict__ clsb,
    float* __restrict__ out)
{
  int t = blockIdx.x;
  int tid = threadIdx.x;
  if (tid >= 128) return;
  int b = tid >> 1, o = tid & 1;
  if (t == 0) {
    out[((long)b * NT) * 2 + o] = o ? 1.f : -1.f;
    return;
  }
  const bf16x8* xp = (const bf16x8*)(L16 + ((long)b * NT + t) * 1536);
  const float* w = clsW + o * 2304 + HD;
  float s = clsb[o];
  for (int k = 0; k < 192; ++k) {
    bf16x8 v = xp[k];
    #pragma unroll
    for (int e = 0; e < 8; ++e)
      s += bf2f((unsigned short)v[e]) * w[k * 8 + e];
  }
  out[((long)b * NT + t) * 2 + o] = s;
}

// ---------------------------------------------------------------------------
// Phase 2 persistent: 192 blocks (0-95 subword chain, 96-191 word chain),
// producer-consumer: word step s overlaps subword step s+1.
// ---------------------------------------------------------------------------
__global__ __launch_bounds__(256, 1) void stack_persist(
    const __hip_bfloat16* __restrict__ L16,
    const __hip_bfloat16* __restrict__ WS,
    const __hip_bfloat16* __restrict__ WW,
    const float* __restrict__ bS, const float* __restrict__ bW,
    const int* __restrict__ golds,
    const float* __restrict__ clsW,
    __hip_bfloat16* __restrict__ H1S,   // [2][64][768]
    __hip_bfloat16* __restrict__ H2S,   // [2][64][768]
    __hip_bfloat16* __restrict__ SUBW,  // [2][64][1536]
    float* __restrict__ out,
    int* __restrict__ bars)             // +32: cntS, +48: cntW
{
  __shared__ unsigned short Wl[32 * 2304];  // 144 KiB
  __shared__ float gl[64][33];
  int blk = blockIdx.x, role = blk / 96, nt = blk % 96;
  int* cntS = bars + 32;
  int* cntW = bars + 48;
  const float* bias = role ? bW : bS;
  load_W_lds(Wl, role ? WW : WS, nt * 32, 2304);
  int tid = threadIdx.x;

  int b_[2], jj_[2], j_[2]; float bv[2][4];
  #pragma unroll
  for (int u = 0; u < 2; ++u) {
    int e = tid * 2 + u;
    b_[u] = e >> 3; jj_[u] = e & 7; j_[u] = nt * 8 + jj_[u];
    bv[u][0] = bias[j_[u]];          bv[u][1] = bias[HD + j_[u]];
    bv[u][2] = bias[2 * HD + j_[u]]; bv[u][3] = bias[3 * HD + j_[u]];
  }
  float cst[2] = {0.f, 0.f};
  float hreg[2] = {0.f, 0.f};
  __hip_bfloat16 zb = __float2bfloat16(0.f);
  __syncthreads();

  if (role == 0) {
    // ---- subword chain ----
    for (int s = 0; s < NT - 1; ++s) {
      int par = s & 1;
      // SUBW[par] must be free: word finished step s-2
      if (s >= 2) group_wait(cntW, 96 * (s - 1), false);
      mfma_gates_lds(Wl, 4608, 72, 1536,
                     L16 + (long)s * 1536, (long)NT * 1536,
                     H1S + (long)par * (NB * HD), gl);
      __syncthreads();
      #pragma unroll
      for (int u = 0; u < 2; ++u) {
        float vi = gl[b_[u]][4 * jj_[u] + 0] + bv[u][0];
        float vf = gl[b_[u]][4 * jj_[u] + 1] + bv[u][1];
        float vg = gl[b_[u]][4 * jj_[u] + 2] + bv[u][2];
        float vo = gl[b_[u]][4 * jj_[u] + 3] + bv[u][3];
        float si = fast_sig(vi), sf = fast_sig(vf), so = fast_sig(vo);
        float tg = fast_tanh(vg);
        float c1 = sf * cst[u] + si * tg;
        float h1 = so * fast_tanh(c1);
        __hip_bfloat16 h1b = __float2bfloat16(h1);
        __hip_bfloat16 c1b = __float2bfloat16(c1);
        long sb = (long)par * (NB * 1536) + b_[u] * 1536 + j_[u];
        SUBW[sb]      = h1b;
        SUBW[sb + HD] = c1b;
        int g = golds[b_[u] * NT + s + 1];
        bool push = (g == 0);
        H1S[(long)(par ^ 1) * (NB * HD) + b_[u] * HD + j_[u]] = push ? h1b : zb;
        cst[u] = push ? c1 : 0.f;
      }
      group_barrier(cntS, 96 * (s + 1), s < NT - 2);
    }
  } else {
    // ---- word chain ----
    for (int s = 0; s < NT - 1; ++s) {
      int par = s & 1;
      group_wait(cntS, 96 * (s + 1), true);   // subword step s visible
      mfma_gates_lds(Wl, 4608, 72, 1536,
                     SUBW + (long)par * (NB * 1536), 1536,
                     H2S + (long)par * (NB * HD), gl);
      __syncthreads();
      float p0 = 0.f, p1 = 0.f;
      #pragma unroll
      for (int u = 0; u < 2; ++u) {
        float vi = gl[b_[u]][4 * jj_[u] + 0] + bv[u][0];
        float vf = gl[b_[u]][4 * jj_[u] + 1] + bv[u][1];
        float vg = gl[b_[u]][4 * jj_[u] + 2] + bv[u][2];
        float vo = gl[b_[u]][4 * jj_[u] + 3] + bv[u][3];
        float si = fast_sig(vi), sf = fast_sig(vf), so = fast_sig(vo);
        float tg = fast_tanh(vg);
        float c2 = sf * cst[u] + si * tg;
        float h2 = so * fast_tanh(c2);
        int g = golds[b_[u] * NT + s + 1];
        bool push = (g >= 1);
        cst[u]  = push ? c2 : cst[u];
        hreg[u] = push ? h2 : hreg[u];
        H2S[(long)(par ^ 1) * (NB * HD) + b_[u] * HD + j_[u]] = __float2bfloat16(hreg[u]);
        p0 += h2 * clsW[j_[u]];
        p1 += h2 * clsW[2304 + j_[u]];
      }
      p0 += __shfl_down(p0, 1); p1 += __shfl_down(p1, 1);
      p0 += __shfl_down(p0, 2); p1 += __shfl_down(p1, 2);
      if ((tid & 3) == 0) {
        int b = tid >> 2;
        atomicAdd(&out[((long)b * NT + s + 1) * 2 + 0], p0);
        atomicAdd(&out[((long)b * NT + s + 1) * 2 + 1], p1);
      }
      if (s < NT - 2) group_barrier(cntW, 96 * (s + 1), true);
    }
  }
}

// ---------------------------------------------------------------------------
// Host launcher
// ---------------------------------------------------------------------------
extern "C" void kernel_launch(void* const* d_in, const int* in_sizes, int n_in,
                              void* d_out, int out_size, void* d_ws, size_t ws_size,
                              hipStream_t stream)
{
  const float* x     = (const float*)d_in[0];
  const int*   golds = (const int*)d_in[1];
  const float* WihF  = (const float*)d_in[2];
  const float* WhhF  = (const float*)d_in[3];
  const float* bF    = (const float*)d_in[4];
  const float* WihB  = (const float*)d_in[5];
  const float* WhhB  = (const float*)d_in[6];
  const float* bB    = (const float*)d_in[7];
  const float* WihS  = (const float*)d_in[8];
  const float* WhhS  = (const float*)d_in[9];
  const float* bS    = (const float*)d_in[10];
  const float* WihW  = (const float*)d_in[11];
  const float* WhhW  = (const float*)d_in[12];
  const float* bW    = (const float*)d_in[13];
  const float* clsW  = (const float*)d_in[14];
  const float* clsb  = (const float*)d_in[15];
  float* out = (float*)d_out;

  // workspace layout (bytes)
  const size_t OFF_X16  = 0;                   // 25165824
  const size_t OFF_WF   = 25165824;            //  9437184
  const size_t OFF_WB   = 34603008;            //  9437184
  const size_t OFF_WS   = 44040192;            // 14155776
  const size_t OFF_WW   = 58195968;            // 14155776
  const size_t OFF_L16  = 72351744;            // 50331648
  const size_t OFF_H16  = 122683392;           //   393216
  const size_t OFF_H1S  = 123076608;           //   196608
  const size_t OFF_H2S  = 123273216;           //   196608
  const size_t OFF_SUBW = 123469824;           //   393216
  const size_t OFF_BARS = 123863040;           //      256
  const size_t WS_NEEDED = 123863296;

  if (ws_size < WS_NEEDED) {
    fill_sentinel<<<(out_size + 255) / 256, 256, 0, stream>>>(out, out_size, 12345.f);
    return;
  }

  char* ws = (char*)d_ws;
  __hip_bfloat16* X16  = (__hip_bfloat16*)(ws + OFF_X16);
  __hip_bfloat16* WF   = (__hip_bfloat16*)(ws + OFF_WF);
  __hip_bfloat16* WB   = (__hip_bfloat16*)(ws + OFF_WB);
  __hip_bfloat16* WSp  = (__hip_bfloat16*)(ws + OFF_WS);
  __hip_bfloat16* WWp  = (__hip_bfloat16*)(ws + OFF_WW);
  __hip_bfloat16* L16  = (__hip_bfloat16*)(ws + OFF_L16);
  __hip_bfloat16* H16  = (__hip_bfloat16*)(ws + OFF_H16);
  __hip_bfloat16* H1S  = (__hip_bfloat16*)(ws + OFF_H1S);
  __hip_bfloat16* H2S  = (__hip_bfloat16*)(ws + OFF_H2S);
  __hip_bfloat16* SUBW = (__hip_bfloat16*)(ws + OFF_SUBW);
  int*            bars = (int*)(ws + OFF_BARS);

  // setup: pack weights, convert x, zero states + barrier counters
  pack_w_kernel<<<2048, 256, 0, stream>>>(WihF, WhhF, WF, 768);
  pack_w_kernel<<<2048, 256, 0, stream>>>(WihB, WhhB, WB, 768);
  pack_w_kernel<<<2048, 256, 0, stream>>>(WihS, WhhS, WSp, 1536);
  pack_w_kernel<<<2048, 256, 0, stream>>>(WihW, WhhW, WWp, 1536);
  cvt_bf16_kernel<<<2048, 256, 0, stream>>>(x, X16, (long)NB * NT * HD);
  hipMemsetAsync(ws + OFF_H16, 0, WS_NEEDED - OFF_H16, stream);

  // phase 1: persistent BiLSTM (256 internal grid-sync steps)
  bilstm_persist<<<192, 256, 0, stream>>>(X16, WF, WB, bF, bB, H16, L16, bars);

  // cls x-part + pred0 (full overwrite of out)
  clsx_kernel<<<NT, 256, 0, stream>>>(L16, clsW, clsb, out);

  // phase 2: persistent stack-LSTM, subword/word chains pipelined
  stack_persist<<<192, 256, 0, stream>>>(L16, WSp, WWp, bS, bW, golds, clsW,
                                         H1S, H2S, SUBW, out, bars);
}

// Round 6
// 10138.097 us; speedup vs baseline: 2.2914x; 1.3299x over previous
//
#include <hip/hip_runtime.h>
#include <hip/hip_bf16.h>

typedef __attribute__((ext_vector_type(8))) short bf16x8;
typedef __attribute__((ext_vector_type(4))) float f32x4;

#define HD   768
#define NB   64
#define NT   256
#define NGATE 3072   // 4*HD
#define FPAD 32      // flag padding: 32 ints = 128 B (one cache line)

__device__ __forceinline__ float fast_sig(float x) { return 1.f / (1.f + __expf(-x)); }
__device__ __forceinline__ float fast_tanh(float x) {
  float t = __expf(-2.f * fabsf(x));
  float r = (1.f - t) / (1.f + t);
  return x < 0.f ? -r : r;
}
__device__ __forceinline__ float bf2f(unsigned short u) {
  union { unsigned i; float f; } v; v.i = ((unsigned)u) << 16; return v.f;
}

// ---------------------------------------------------------------------------
// Flag-array grid sync built ONLY from Round-4-proven primitives:
//   publish: __syncthreads (drains stores) + __threadfence (wbL2) + atomicAdd
//            RMW on the block's OWN 128B line (RMW -> forced to LLC, always
//            visible cross-XCD; plain stores are NOT).
//   wait:    96 threads spin independently on 96 distinct lines (bounded),
//            then barrier, then one __threadfence (inv) AFTER all flags seen.
// ---------------------------------------------------------------------------
__device__ __forceinline__ int aload(int* p) {
  return __hip_atomic_load(p, __ATOMIC_RELAXED, __HIP_MEMORY_SCOPE_AGENT);
}

__device__ __forceinline__ void arrive_flag(int* f) {
  __syncthreads();                 // all block stores drained to L2 (vmcnt(0) before s_barrier)
  if (threadIdx.x == 0) {
    __threadfence();               // seq_cst agent: wbL2 -> coherent point
    __hip_atomic_fetch_add(f, 1, __ATOMIC_RELAXED, __HIP_MEMORY_SCOPE_AGENT);
  }
}

// Wait until all 96 flags in fa >= ta AND (fb: all 96 flags in fb >= tb).
// Threads 0..95 poll fa, threads 128..223 poll fb. Bounded spin -> fast-fail.
__device__ __forceinline__ void wait2(int* fa, int ta, int* fb, int tb) {
  int tid = threadIdx.x;
  int* p = nullptr; int tgt = 0;
  if (tid < 96)                            { p = fa + tid * FPAD;         tgt = ta; }
  else if (fb && tid >= 128 && tid < 224)  { p = fb + (tid - 128) * FPAD; tgt = tb; }
  if (p && tgt > 0) {
    int guard = 0;
    while (aload(p) < tgt) {
      __builtin_amdgcn_s_sleep(1);
      if (++guard > (1 << 17)) break;      // deadlock -> wrong answer fast, not 600s hang
    }
  }
  __syncthreads();                 // all flags observed
  if (tid == 0) __threadfence();   // inv L1/L2 strictly after all producers released
  __syncthreads();
}

// ---------------------------------------------------------------------------
// Load a 32-row weight slice into LDS, XOR-swizzled:
//   lds_byte(r, cb) = r*K*2 + (cb ^ ((r&7)<<4))
// ---------------------------------------------------------------------------
__device__ __forceinline__ void load_W_lds(unsigned short* Wl,
                                           const __hip_bfloat16* Wg,
                                           int n_base, int K)
{
  int chunksPerRow = (K * 2) / 16;
  int total = 32 * chunksPerRow;
  for (int idx = threadIdx.x; idx < total; idx += 256) {
    int r  = idx / chunksPerRow;
    int cb = (idx % chunksPerRow) * 16;
    bf16x8 v = *(const bf16x8*)((const char*)(Wg + (long)(n_base + r) * K) + cb);
    *(bf16x8*)((char*)Wl + (long)r * (K * 2) + (cb ^ ((r & 7) << 4))) = v;
  }
}

// ---------------------------------------------------------------------------
// Per-step GEMM, B from swizzled LDS: gates[b][n'] = sum_k A[b][k]*W[n'][k]
// A split: k<K0 -> A0 (strideA0), k>=K0 -> A1 (stride 768). Result in gl.
// ---------------------------------------------------------------------------
__device__ __forceinline__ void mfma_gates_lds(
    const unsigned short* Wl, int Kbytes, int nIter, int K0,
    const __hip_bfloat16* __restrict__ A0, long strideA0,
    const __hip_bfloat16* __restrict__ A1,
    float (*gl)[33])
{
  int tid = threadIdx.x;
  int w = tid >> 6, l = tid & 63, lr = l & 15, lh = l >> 4;
  f32x4 acc0 = {0.f, 0.f, 0.f, 0.f};
  f32x4 acc1 = {0.f, 0.f, 0.f, 0.f};
  int bA = 16 * w + lr;
  const __hip_bfloat16* a0p = A0 + (long)bA * strideA0;
  const __hip_bfloat16* a1p = A1 + bA * HD - K0;
  const char* w0 = (const char*)Wl + lr * Kbytes;
  const char* w1 = (const char*)Wl + (16 + lr) * Kbytes;
  int xr = (lr & 7) << 4;
  int kk = 8 * lh;
  #pragma unroll 4
  for (int it = 0; it < nIter; ++it) {
    int ka = it * 32 + kk;
    const __hip_bfloat16* ap = (ka < K0) ? (a0p + ka) : (a1p + ka);
    bf16x8 av = *(const bf16x8*)ap;
    int o = (ka * 2) ^ xr;
    bf16x8 bv0 = *(const bf16x8*)(w0 + o);
    bf16x8 bv1 = *(const bf16x8*)(w1 + o);
    acc0 = __builtin_amdgcn_mfma_f32_16x16x32_bf16(av, bv0, acc0, 0, 0, 0);
    acc1 = __builtin_amdgcn_mfma_f32_16x16x32_bf16(av, bv1, acc1, 0, 0, 0);
  }
  #pragma unroll
  for (int r = 0; r < 4; ++r) {
    gl[16 * w + 4 * lh + r][lr]      = acc0[r];
    gl[16 * w + 4 * lh + r][16 + lr] = acc1[r];
  }
}

// ---------------------------------------------------------------------------
// Setup kernels
// ---------------------------------------------------------------------------
__global__ void cvt_bf16_kernel(const float* __restrict__ src,
                                __hip_bfloat16* __restrict__ dst, long n)
{
  long i = (long)blockIdx.x * blockDim.x + threadIdx.x;
  long stride = (long)gridDim.x * blockDim.x;
  for (; i < n; i += stride) dst[i] = __float2bfloat16(src[i]);
}

// dst[n'][k], n' = j*4 + g; k < Kih -> Wih, else Whh
__global__ void pack_w_kernel(const float* __restrict__ Wih,
                              const float* __restrict__ Whh,
                              __hip_bfloat16* __restrict__ dst, int Kih)
{
  int K = Kih + HD;
  long total = (long)NGATE * K;
  long stride = (long)gridDim.x * blockDim.x;
  for (long idx = (long)blockIdx.x * blockDim.x + threadIdx.x; idx < total; idx += stride) {
    int np = (int)(idx / K), k = (int)(idx % K);
    int j = np >> 2, g = np & 3;
    int n = g * HD + j;
    float v = (k < Kih) ? Wih[(long)n * Kih + k] : Whh[(long)n * HD + (k - Kih)];
    dst[idx] = __float2bfloat16(v);
  }
}

__global__ void fill_sentinel(float* out, int n, float v)
{
  int i = blockIdx.x * blockDim.x + threadIdx.x;
  if (i < n) out[i] = v;
}

// ---------------------------------------------------------------------------
// Phase 1 persistent: BiLSTM, 192 blocks (0-95 fwd, 96-191 bwd), 256 steps.
// W-slice in LDS; c-state in registers; h double-buffered in global;
// per-direction flag-array barrier each step.
// ---------------------------------------------------------------------------
__global__ __launch_bounds__(256, 1) void bilstm_persist(
    const __hip_bfloat16* __restrict__ X16,   // [64][256][768]
    const __hip_bfloat16* __restrict__ WF,
    const __hip_bfloat16* __restrict__ WB,
    const float* __restrict__ bF, const float* __restrict__ bB,
    __hip_bfloat16* __restrict__ H16,         // [2 par][2 dir][64][768]
    __hip_bfloat16* __restrict__ L16,         // [64][256][1536]
    int* __restrict__ flags)                  // [2 dir][96*FPAD]
{
  __shared__ unsigned short Wl[32 * 1536];    // 96 KiB
  __shared__ float gl[64][33];
  int blk = blockIdx.x, dir = blk / 96, nt = blk % 96;
  load_W_lds(Wl, dir ? WB : WF, nt * 32, 1536);
  const float* bias = dir ? bB : bF;
  int* myflags = flags + dir * 96 * FPAD;
  int tid = threadIdx.x;

  int b_[2], jj_[2], j_[2]; float bv[2][4];
  #pragma unroll
  for (int u = 0; u < 2; ++u) {
    int e = tid * 2 + u;
    b_[u] = e >> 3; jj_[u] = e & 7; j_[u] = nt * 8 + jj_[u];
    bv[u][0] = bias[j_[u]];          bv[u][1] = bias[HD + j_[u]];
    bv[u][2] = bias[2 * HD + j_[u]]; bv[u][3] = bias[3 * HD + j_[u]];
  }
  float cst[2] = {0.f, 0.f};
  __syncthreads();

  for (int s = 0; s < NT; ++s) {
    int par = s & 1;
    int t = dir ? (NT - 1 - s) : s;
    if (s > 0) wait2(myflags, s, nullptr, 0);   // all blocks finished step s-1
    mfma_gates_lds(Wl, 3072, 48, 768,
                   X16 + (long)t * HD, (long)NT * HD,
                   H16 + (long)(par * 2 + dir) * (NB * HD), gl);
    __syncthreads();
    #pragma unroll
    for (int u = 0; u < 2; ++u) {
      float vi = gl[b_[u]][4 * jj_[u] + 0] + bv[u][0];
      float vf = gl[b_[u]][4 * jj_[u] + 1] + bv[u][1];
      float vg = gl[b_[u]][4 * jj_[u] + 2] + bv[u][2];
      float vo = gl[b_[u]][4 * jj_[u] + 3] + bv[u][3];
      float si = fast_sig(vi), sf = fast_sig(vf), so = fast_sig(vo);
      float tg = fast_tanh(vg);
      float c = sf * cst[u] + si * tg;
      cst[u] = c;
      float h = so * fast_tanh(c);
      __hip_bfloat16 hb = __float2bfloat16(h);
      H16[(long)((par ^ 1) * 2 + dir) * (NB * HD) + b_[u] * HD + j_[u]] = hb;
      L16[((long)b_[u] * NT + t) * 1536 + dir * HD + j_[u]] = hb;
    }
    if (s < NT - 1) arrive_flag(myflags + nt * FPAD);
  }
}

// ---------------------------------------------------------------------------
// cls x-part (vectorized) + pred0
// ---------------------------------------------------------------------------
__global__ __launch_bounds__(256) void clsx_kernel(
    const __hip_bfloat16* __restrict__ L16,
    const float* __restrict__ clsW, const float* __restrict__ clsb,
    float* __restrict__ out)
{
  int t = blockIdx.x;
  int tid = threadIdx.x;
  if (tid >= 128) return;
  int b = tid >> 1, o = tid & 1;
  if (t == 0) {
    out[((long)b * NT) * 2 + o] = o ? 1.f : -1.f;
    return;
  }
  const bf16x8* xp = (const bf16x8*)(L16 + ((long)b * NT + t) * 1536);
  const float* w = clsW + o * 2304 + HD;
  float s = clsb[o];
  for (int k = 0; k < 192; ++k) {
    bf16x8 v = xp[k];
    #pragma unroll
    for (int e = 0; e < 8; ++e)
      s += bf2f((unsigned short)v[e]) * w[k * 8 + e];
  }
  out[((long)b * NT + t) * 2 + o] = s;
}

// ---------------------------------------------------------------------------
// Phase 2 persistent: 192 blocks (0-95 subword chain, 96-191 word chain),
// producer-consumer via 4-deep SUBW ring + flag arrays.
//   subword step s: needs flagS>=s (h1 exchange), flagW>=s-3 (ring free)
//   word    step s: needs flagS>=s+1 (SUBW[s] ready), flagW>=s (h2 exchange)
// ---------------------------------------------------------------------------
__global__ __launch_bounds__(256, 1) void stack_persist(
    const __hip_bfloat16* __restrict__ L16,
    const __hip_bfloat16* __restrict__ WS,
    const __hip_bfloat16* __restrict__ WW,
    const float* __restrict__ bS, const float* __restrict__ bW,
    const int* __restrict__ golds,
    const float* __restrict__ clsW,
    __hip_bfloat16* __restrict__ H1S,   // [2][64][768]
    __hip_bfloat16* __restrict__ H2S,   // [2][64][768]
    __hip_bfloat16* __restrict__ SUBW,  // [4][64][1536] ring
    float* __restrict__ out,
    int* __restrict__ flags)            // [+2*96*FPAD: S] [+3*96*FPAD: W]
{
  __shared__ unsigned short Wl[32 * 2304];  // 144 KiB
  __shared__ float gl[64][33];
  int blk = blockIdx.x, role = blk / 96, nt = blk % 96;
  int* flagS = flags + 2 * 96 * FPAD;
  int* flagW = flags + 3 * 96 * FPAD;
  const float* bias = role ? bW : bS;
  load_W_lds(Wl, role ? WW : WS, nt * 32, 2304);
  int tid = threadIdx.x;

  int b_[2], jj_[2], j_[2]; float bv[2][4];
  #pragma unroll
  for (int u = 0; u < 2; ++u) {
    int e = tid * 2 + u;
    b_[u] = e >> 3; jj_[u] = e & 7; j_[u] = nt * 8 + jj_[u];
    bv[u][0] = bias[j_[u]];          bv[u][1] = bias[HD + j_[u]];
    bv[u][2] = bias[2 * HD + j_[u]]; bv[u][3] = bias[3 * HD + j_[u]];
  }
  float cst[2] = {0.f, 0.f};
  float hreg[2] = {0.f, 0.f};
  __hip_bfloat16 zb = __float2bfloat16(0.f);
  __syncthreads();

  if (role == 0) {
    // ---- subword chain ----
    for (int s = 0; s < NT - 1; ++s) {
      wait2(flagS, s, flagW, s - 3);
      mfma_gates_lds(Wl, 4608, 72, 1536,
                     L16 + (long)s * 1536, (long)NT * 1536,
                     H1S + (long)(s & 1) * (NB * HD), gl);
      __syncthreads();
      #pragma unroll
      for (int u = 0; u < 2; ++u) {
        float vi = gl[b_[u]][4 * jj_[u] + 0] + bv[u][0];
        float vf = gl[b_[u]][4 * jj_[u] + 1] + bv[u][1];
        float vg = gl[b_[u]][4 * jj_[u] + 2] + bv[u][2];
        float vo = gl[b_[u]][4 * jj_[u] + 3] + bv[u][3];
        float si = fast_sig(vi), sf = fast_sig(vf), so = fast_sig(vo);
        float tg = fast_tanh(vg);
        float c1 = sf * cst[u] + si * tg;
        float h1 = so * fast_tanh(c1);
        __hip_bfloat16 h1b = __float2bfloat16(h1);
        __hip_bfloat16 c1b = __float2bfloat16(c1);
        long sb = (long)(s & 3) * (NB * 1536) + b_[u] * 1536 + j_[u];
        SUBW[sb]      = h1b;
        SUBW[sb + HD] = c1b;
        int g = golds[b_[u] * NT + s + 1];
        bool push = (g == 0);
        H1S[(long)((s + 1) & 1) * (NB * HD) + b_[u] * HD + j_[u]] = push ? h1b : zb;
        cst[u] = push ? c1 : 0.f;
      }
      arrive_flag(flagS + nt * FPAD);
    }
  } else {
    // ---- word chain ----
    for (int s = 0; s < NT - 1; ++s) {
      wait2(flagS, s + 1, flagW, s);
      mfma_gates_lds(Wl, 4608, 72, 1536,
                     SUBW + (long)(s & 3) * (NB * 1536), 1536,
                     H2S + (long)(s & 1) * (NB * HD), gl);
      __syncthreads();
      float p0 = 0.f, p1 = 0.f;
      #pragma unroll
      for (int u = 0; u < 2; ++u) {
        float vi = gl[b_[u]][4 * jj_[u] + 0] + bv[u][0];
        float vf = gl[b_[u]][4 * jj_[u] + 1] + bv[u][1];
        float vg = gl[b_[u]][4 * jj_[u] + 2] + bv[u][2];
        float vo = gl[b_[u]][4 * jj_[u] + 3] + bv[u][3];
        float si = fast_sig(vi), sf = fast_sig(vf), so = fast_sig(vo);
        float tg = fast_tanh(vg);
        float c2 = sf * cst[u] + si * tg;
        float h2 = so * fast_tanh(c2);
        int g = golds[b_[u] * NT + s + 1];
        bool push = (g >= 1);
        cst[u]  = push ? c2 : cst[u];
        hreg[u] = push ? h2 : hreg[u];
        H2S[(long)((s + 1) & 1) * (NB * HD) + b_[u] * HD + j_[u]] = __float2bfloat16(hreg[u]);
        p0 += h2 * clsW[j_[u]];
        p1 += h2 * clsW[2304 + j_[u]];
      }
      p0 += __shfl_down(p0, 1); p1 += __shfl_down(p1, 1);
      p0 += __shfl_down(p0, 2); p1 += __shfl_down(p1, 2);
      if ((tid & 3) == 0) {
        int b = tid >> 2;
        atomicAdd(&out[((long)b * NT + s + 1) * 2 + 0], p0);
        atomicAdd(&out[((long)b * NT + s + 1) * 2 + 1], p1);
      }
      if (s < NT - 2) arrive_flag(flagW + nt * FPAD);
    }
  }
}

// ---------------------------------------------------------------------------
// Host launcher
// ---------------------------------------------------------------------------
extern "C" void kernel_launch(void* const* d_in, const int* in_sizes, int n_in,
                              void* d_out, int out_size, void* d_ws, size_t ws_size,
                              hipStream_t stream)
{
  const float* x     = (const float*)d_in[0];
  const int*   golds = (const int*)d_in[1];
  const float* WihF  = (const float*)d_in[2];
  const float* WhhF  = (const float*)d_in[3];
  const float* bF    = (const float*)d_in[4];
  const float* WihB  = (const float*)d_in[5];
  const float* WhhB  = (const float*)d_in[6];
  const float* bB    = (const float*)d_in[7];
  const float* WihS  = (const float*)d_in[8];
  const float* WhhS  = (const float*)d_in[9];
  const float* bS    = (const float*)d_in[10];
  const float* WihW  = (const float*)d_in[11];
  const float* WhhW  = (const float*)d_in[12];
  const float* bW    = (const float*)d_in[13];
  const float* clsW  = (const float*)d_in[14];
  const float* clsb  = (const float*)d_in[15];
  float* out = (float*)d_out;

  // workspace layout (bytes)
  const size_t OFF_X16  = 0;                   // 25165824
  const size_t OFF_WF   = 25165824;            //  9437184
  const size_t OFF_WB   = 34603008;            //  9437184
  const size_t OFF_WS   = 44040192;            // 14155776
  const size_t OFF_WW   = 58195968;            // 14155776
  const size_t OFF_L16  = 72351744;            // 50331648
  const size_t OFF_H16  = 122683392;           //   393216
  const size_t OFF_H1S  = 123076608;           //   196608
  const size_t OFF_H2S  = 123273216;           //   196608
  const size_t OFF_SUBW = 123469824;           //   786432 (4-deep ring)
  const size_t OFF_FLG  = 124256256;           //    49152 (4*96*128B)
  const size_t WS_NEEDED = 124305408;

  if (ws_size < WS_NEEDED) {
    fill_sentinel<<<(out_size + 255) / 256, 256, 0, stream>>>(out, out_size, 12345.f);
    return;
  }

  char* ws = (char*)d_ws;
  __hip_bfloat16* X16  = (__hip_bfloat16*)(ws + OFF_X16);
  __hip_bfloat16* WF   = (__hip_bfloat16*)(ws + OFF_WF);
  __hip_bfloat16* WB   = (__hip_bfloat16*)(ws + OFF_WB);
  __hip_bfloat16* WSp  = (__hip_bfloat16*)(ws + OFF_WS);
  __hip_bfloat16* WWp  = (__hip_bfloat16*)(ws + OFF_WW);
  __hip_bfloat16* L16  = (__hip_bfloat16*)(ws + OFF_L16);
  __hip_bfloat16* H16  = (__hip_bfloat16*)(ws + OFF_H16);
  __hip_bfloat16* H1S  = (__hip_bfloat16*)(ws + OFF_H1S);
  __hip_bfloat16* H2S  = (__hip_bfloat16*)(ws + OFF_H2S);
  __hip_bfloat16* SUBW = (__hip_bfloat16*)(ws + OFF_SUBW);
  int*            flags= (int*)(ws + OFF_FLG);

  // setup: pack weights, convert x, zero states + flags
  pack_w_kernel<<<2048, 256, 0, stream>>>(WihF, WhhF, WF, 768);
  pack_w_kernel<<<2048, 256, 0, stream>>>(WihB, WhhB, WB, 768);
  pack_w_kernel<<<2048, 256, 0, stream>>>(WihS, WhhS, WSp, 1536);
  pack_w_kernel<<<2048, 256, 0, stream>>>(WihW, WhhW, WWp, 1536);
  cvt_bf16_kernel<<<2048, 256, 0, stream>>>(x, X16, (long)NB * NT * HD);
  hipMemsetAsync(ws + OFF_H16, 0, WS_NEEDED - OFF_H16, stream);

  // phase 1: persistent BiLSTM (256 internal flag-sync steps)
  bilstm_persist<<<192, 256, 0, stream>>>(X16, WF, WB, bF, bB, H16, L16, flags);

  // cls x-part + pred0 (full overwrite of out)
  clsx_kernel<<<NT, 256, 0, stream>>>(L16, clsW, clsb, out);

  // phase 2: persistent stack-LSTM, subword/word chains pipelined
  stack_persist<<<192, 256, 0, stream>>>(L16, WSp, WWp, bS, bW, golds, clsW,
                                         H1S, H2S, SUBW, out, flags);
}